// Round 7
// baseline (475.614 us; speedup 1.0000x reference)
//
#include <hip/hip_runtime.h>
#include <stdint.h>

#define BB 128
#define TT 256
#define CC 384
#define HH 6
#define DD 64
#define FFF 1536
#define ROWS (BB*TT)   // 32768

typedef unsigned short u16;
typedef __bf16 bf8v __attribute__((ext_vector_type(8)));
typedef float f4v __attribute__((ext_vector_type(4)));

__device__ __forceinline__ float bf2f(u16 u) {
    unsigned int v = ((unsigned int)u) << 16;
    float f;
    __builtin_memcpy(&f, &v, 4);
    return f;
}
__device__ __forceinline__ u16 f2bf(float f) {
    unsigned int u;
    __builtin_memcpy(&u, &f, 4);
    u += 0x7fffu + ((u >> 16) & 1u);   // RNE; inputs finite
    return (u16)(u >> 16);
}

// async global->LDS 16B per lane; LDS dest must be wave-uniform base + lane*16
__device__ __forceinline__ void gload_lds16(const void* g, void* l) {
    __builtin_amdgcn_global_load_lds(
        (__attribute__((address_space(1))) void*)(g),
        (__attribute__((address_space(3))) void*)(l), 16, 0, 0);
}

// ---------------- LayerNorm: fp32 in -> bf16 out (1 wave per row of 384) ------
__device__ __forceinline__ void ln_body(
    int row, const float* __restrict__ x, const float* __restrict__ g,
    const float* __restrict__ b, u16* __restrict__ out, int lane)
{
    const float* xr = x + (long long)row * CC;
    float v[6]; float s = 0.f;
#pragma unroll
    for (int i = 0; i < 6; ++i) { v[i] = xr[lane + i * 64]; s += v[i]; }
#pragma unroll
    for (int o = 32; o > 0; o >>= 1) s += __shfl_xor(s, o);
    const float mu = s * (1.f / CC);
    float q = 0.f;
#pragma unroll
    for (int i = 0; i < 6; ++i) { float d = v[i] - mu; q += d * d; }
#pragma unroll
    for (int o = 32; o > 0; o >>= 1) q += __shfl_xor(q, o);
    const float inv = rsqrtf(q * (1.f / CC) + 1e-5f);
    u16* orow = out + (long long)row * CC;
#pragma unroll
    for (int i = 0; i < 6; ++i) {
        int c = lane + i * 64;
        orow[c] = f2bf((v[i] - mu) * inv * g[c] + b[c]);
    }
}

__global__ __launch_bounds__(256) void ln_kernel(
    const float* __restrict__ x, const float* __restrict__ g,
    const float* __restrict__ b, u16* __restrict__ out)
{
    ln_body(blockIdx.x * 4 + (threadIdx.x >> 6), x, g, b, out, threadIdx.x & 63);
}

// ---------------- fused LN1 + weight convert (independent work, one dispatch) -
__global__ __launch_bounds__(256) void ln1_cvt_kernel(
    const float* __restrict__ x, const float* __restrict__ ln1g, const float* __restrict__ ln1b,
    u16* __restrict__ h,
    const float* __restrict__ Wq, const float* __restrict__ Wk, const float* __restrict__ Wv,
    const float* __restrict__ bq, const float* __restrict__ bk, const float* __restrict__ bv,
    const float* __restrict__ Wp, const float* __restrict__ W1, const float* __restrict__ W2,
    u16* __restrict__ wqkvT, u16* __restrict__ wpT, u16* __restrict__ w1T,
    u16* __restrict__ w2T, float* __restrict__ bqkv)
{
    if (blockIdx.x < ROWS / 4) {
        ln_body(blockIdx.x * 4 + (threadIdx.x >> 6), x, ln1g, ln1b, h, threadIdx.x & 63);
        return;
    }
    const int S0 = 1152 * 384, S1 = 384 * 384, S2 = 1536 * 384, S3 = 384 * 1536;
    int i = (blockIdx.x - ROWS / 4) * 256 + threadIdx.x;
    if (i < S0) {
        int n = i / 384, k = i % 384;
        const float* W = (n < 384) ? Wq : (n < 768) ? Wk : Wv;
        int nn = (n >= 768) ? n - 768 : (n >= 384) ? n - 384 : n;
        int hh = nn >> 6, d = nn & 63;
        wqkvT[i] = f2bf(W[hh * (384 * 64) + k * 64 + d]);
        return;
    }
    i -= S0;
    if (i < S1) { int n = i / 384, k = i % 384; wpT[i] = f2bf(Wp[k * 384 + n]); return; }
    i -= S1;
    if (i < S2) { int n = i / 384, k = i % 384; w1T[i] = f2bf(W1[k * 1536 + n]); return; }
    i -= S2;
    if (i < S3) { int n = i / 1536, k = i % 1536; w2T[i] = f2bf(W2[k * 384 + n]); return; }
    i -= S3;
    if (i < 1152) bqkv[i] = (i < 384) ? bq[i] : (i < 768) ? bk[i - 384] : bv[i - 768];
}

// ---------------- V transpose: qkv (b,t,h,d) V-cols -> vt (b,h,d,t) ----------
__global__ __launch_bounds__(256) void vtrans_kernel(
    const u16* __restrict__ qkv, u16* __restrict__ vt)
{
    __shared__ u16 tile[64][65];
    const int z = blockIdx.x;          // b*H + h
    const int tb = blockIdx.y;         // t-block of 64
    const int zb = z / HH, zh = z % HH;
    const u16* src = qkv + ((long long)(zb * TT + tb * 64)) * 1152 + 768 + zh * 64;
    const int tid = threadIdx.x;
#pragma unroll
    for (int it = 0; it < 16; ++it) {
        int idx = it * 256 + tid; int tl = idx >> 6, d = idx & 63;
        tile[tl][d] = src[(long long)tl * 1152 + d];
    }
    __syncthreads();
    u16* dst = vt + (long long)z * 64 * 256 + tb * 64;
#pragma unroll
    for (int it = 0; it < 16; ++it) {
        int idx = it * 256 + tid; int d = idx >> 6, tl = idx & 63;
        dst[(long long)d * 256 + tl] = tile[tl][d];
    }
}

// ---------------- Fused flash-style causal attention --------------------------
// R7: 64-row quarter blocks (was 128-row halves). Causal granularity 64 keys
// -> 17% less attended work; flat grid with q = blk&3 interleaves long/short
// blocks for balance. Each wave owns a 16-row strip; no barriers.
__global__ __launch_bounds__(256) void flash_kernel(
    const u16* __restrict__ qkv, const u16* __restrict__ vt, u16* __restrict__ attnout)
{
    __shared__ __align__(16) u16 Pl[64 * 72];   // 9.2 KB; stride 72 keeps rows 16B-aligned

    const int blk = blockIdx.x;
    const int bh = blk >> 2, q = blk & 3;   // q: which 64-row quarter of t
    const int b = bh / HH, hh = bh % HH;
    const int tid = threadIdx.x;
    const int wave = tid >> 6, lane = tid & 63;
    const int quad = lane >> 4, lq = lane & 15;
    const int t0 = q * 64;

    const long long qrow = (long long)b * TT * 1152;
    const u16* Kb  = qkv + qrow + 384 + hh * 64;   // K segment cols
    const u16* Qb  = qkv + qrow + hh * 64;         // Q segment cols
    const u16* Vtb = vt + (long long)bh * (DD * TT);

    // K fragments for this wave's 16-row strip (A operand), loaded once
    bf8v af[2];
#pragma unroll
    for (int ks = 0; ks < 2; ++ks)
        af[ks] = *(const bf8v*)(Kb + (long long)(t0 + wave * 16 + lq) * 1152
                                    + ks * 32 + quad * 8);

    float m_run[4], l_run[4];
    f4v oacc[4];
#pragma unroll
    for (int r = 0; r < 4; ++r) { m_run[r] = -1e30f; l_run[r] = 0.f; }
#pragma unroll
    for (int j = 0; j < 4; ++j) oacc[j] = (f4v){0.f, 0.f, 0.f, 0.f};

    const float scs = 0.05103103630798287f;  // 384^-0.5 (faithful quirk)
    const int ntiles = q + 1;                // causal: quarter q attends s < 64*(q+1)
    for (int st = 0; st < ntiles; ++st) {
        const int s0 = st * 64;
        // ---- S-tile: 16 rows x 64 s, K=64 ----
        f4v sacc[4];
#pragma unroll
        for (int j = 0; j < 4; ++j) sacc[j] = (f4v){0.f, 0.f, 0.f, 0.f};
#pragma unroll
        for (int ks = 0; ks < 2; ++ks) {
            bf8v bq[4];
#pragma unroll
            for (int j = 0; j < 4; ++j)
                bq[j] = *(const bf8v*)(Qb + (long long)(s0 + j * 16 + lq) * 1152
                                          + ks * 32 + quad * 8);
#pragma unroll
            for (int j = 0; j < 4; ++j)
                sacc[j] = __builtin_amdgcn_mfma_f32_16x16x32_bf16(af[ks], bq[j], sacc[j], 0, 0, 0);
        }
        // ---- scale + causal mask (C layout: row=quad*4+r, col=lq) ----
#pragma unroll
        for (int j = 0; j < 4; ++j)
#pragma unroll
            for (int r = 0; r < 4; ++r) {
                int t_g = t0 + wave * 16 + quad * 4 + r;
                int s_g = s0 + j * 16 + lq;
                float v = sacc[j][r] * scs;
                sacc[j][r] = (s_g <= t_g) ? v : -1e30f;
            }
        // ---- online softmax (per row r; row spans j x lq = 16 lanes of this quad) --
#pragma unroll
        for (int r = 0; r < 4; ++r) {
            float mt = sacc[0][r];
#pragma unroll
            for (int j = 1; j < 4; ++j) mt = fmaxf(mt, sacc[j][r]);
#pragma unroll
            for (int o = 8; o > 0; o >>= 1) mt = fmaxf(mt, __shfl_xor(mt, o));
            const float mn = fmaxf(m_run[r], mt);
            const float alpha = __expf(m_run[r] - mn);
            float rs = 0.f;
#pragma unroll
            for (int j = 0; j < 4; ++j) {
                float e = __expf(sacc[j][r] - mn);
                sacc[j][r] = e; rs += e;
            }
#pragma unroll
            for (int o = 8; o > 0; o >>= 1) rs += __shfl_xor(rs, o);
            m_run[r] = mn;
            l_run[r] = l_run[r] * alpha + rs;
#pragma unroll
            for (int j = 0; j < 4; ++j) oacc[j][r] *= alpha;
        }
        // ---- P: C layout -> A layout via wave-private LDS strip (no barrier) ----
#pragma unroll
        for (int j = 0; j < 4; ++j)
#pragma unroll
            for (int r = 0; r < 4; ++r)
                Pl[(wave * 16 + quad * 4 + r) * 72 + j * 16 + lq] = f2bf(sacc[j][r]);
        // ---- PV partial: out += P(16x64) @ V(64x64), B^T = Vt ----
#pragma unroll
        for (int ks2 = 0; ks2 < 2; ++ks2) {
            bf8v ap = *(const bf8v*)(Pl + (wave * 16 + lq) * 72 + ks2 * 32 + quad * 8);
            bf8v bv_[4];
#pragma unroll
            for (int j = 0; j < 4; ++j)
                bv_[j] = *(const bf8v*)(Vtb + (long long)(j * 16 + lq) * 256 + s0 + ks2 * 32 + quad * 8);
#pragma unroll
            for (int j = 0; j < 4; ++j)
                oacc[j] = __builtin_amdgcn_mfma_f32_16x16x32_bf16(ap, bv_[j], oacc[j], 0, 0, 0);
        }
    }
    // ---- epilogue: normalize by l, scatter into (b,t,h*64+d) ----
#pragma unroll
    for (int r = 0; r < 4; ++r) {
        const float inv = 1.f / l_run[r];
        u16* orow = attnout + ((long long)(b * TT + t0 + wave * 16 + quad * 4 + r)) * CC + hh * 64;
#pragma unroll
        for (int j = 0; j < 4; ++j)
            orow[j * 16 + lq] = f2bf(oacc[j][r] * inv);
    }
}

// ---------------- Generic bf16 MFMA GEMM: C = scale*(A @ B^T) [+bias][+res][relu]
// R6-proven: BK=32, global_load_lds width-16, XOR granule swizzle (0 bank
// conflicts). Structure is drain-limited at thin K (m97 plateau) — do not
// re-tweak the inner loop (m131-m141 all neutral/regressed).
template<int BM, int BN, bool OUTBF, bool RELU, bool HASRES>
__global__ __launch_bounds__(256) void gemm_bt(
    const u16* __restrict__ A, const u16* __restrict__ Bw, void* __restrict__ Cp,
    const float* __restrict__ bias, const float* __restrict__ res,
    int K, int lda, int ldb, int ldc,
    long long sAb, long long sAh, long long sBb, long long sBh,
    long long sCb, long long sCh, int Hb, float scale)
{
    __shared__ __align__(16) u16 As[BM * 32];
    __shared__ __align__(16) u16 Bs[BN * 32];

    const int tid = threadIdx.x;
    const int wave = tid >> 6, lane = tid & 63;
    const int quad = lane >> 4, lq = lane & 15;

    const int z = blockIdx.z;
    const int zb = z / Hb, zh = z % Hb;
    const int m0 = blockIdx.x * BM;
    const int n0 = blockIdx.y * BN;

    A  += (long long)zb * sAb + (long long)zh * sAh + (long long)m0 * lda;
    Bw += (long long)zb * sBb + (long long)zh * sBh + (long long)n0 * ldb;
    const long long coff = (long long)zb * sCb + (long long)zh * sCh;

    constexpr int WM = BM / 2, WN = BN / 2;
    constexpr int MT = WM / 16, NT = WN / 16;
    const int wm0 = (wave >> 1) * WM;
    const int wn0 = (wave & 1) * WN;

    f4v acc[MT][NT];
#pragma unroll
    for (int i = 0; i < MT; ++i)
#pragma unroll
        for (int j = 0; j < NT; ++j) acc[i][j] = (f4v){0.f, 0.f, 0.f, 0.f};

    constexpr int AIT = BM / 64;
    constexpr int BIT = BN / 64;

    for (int k0 = 0; k0 < K; k0 += 32) {
        __syncthreads();   // previous iteration's LDS reads complete before overwrite
#pragma unroll
        for (int j = 0; j < AIT; ++j) {
            int idx = j * 256 + tid; int r = idx >> 2, pg = idx & 3;
            int lg = pg ^ ((r >> 1) & 3);        // fetch swizzled granule
            gload_lds16(A + (long long)r * lda + k0 + lg * 8, As + idx * 8);
        }
#pragma unroll
        for (int j = 0; j < BIT; ++j) {
            int idx = j * 256 + tid; int r = idx >> 2, pg = idx & 3;
            int lg = pg ^ ((r >> 1) & 3);
            gload_lds16(Bw + (long long)r * ldb + k0 + lg * 8, Bs + idx * 8);
        }
        __syncthreads();

        bf8v af[MT], bfr[NT];
#pragma unroll
        for (int i = 0; i < MT; ++i) {
            int row = wm0 + i * 16 + lq;
            int pg = quad ^ ((row >> 1) & 3);
            af[i] = *(const bf8v*)(As + row * 32 + pg * 8);
        }
#pragma unroll
        for (int j = 0; j < NT; ++j) {
            int row = wn0 + j * 16 + lq;
            int pg = quad ^ ((row >> 1) & 3);
            bfr[j] = *(const bf8v*)(Bs + row * 32 + pg * 8);
        }
#pragma unroll
        for (int i = 0; i < MT; ++i)
#pragma unroll
            for (int j = 0; j < NT; ++j)
                acc[i][j] = __builtin_amdgcn_mfma_f32_16x16x32_bf16(af[i], bfr[j], acc[i][j], 0, 0, 0);
    }

#pragma unroll
    for (int i = 0; i < MT; ++i) {
#pragma unroll
        for (int j = 0; j < NT; ++j) {
            const int gcol = n0 + wn0 + j * 16 + lq;
            const float bcol = bias ? bias[gcol] : 0.f;
#pragma unroll
            for (int r = 0; r < 4; ++r) {
                const int grow = m0 + wm0 + i * 16 + quad * 4 + r;
                const long long off = coff + (long long)grow * ldc + gcol;
                float v = acc[i][j][r] * scale + bcol;
                if (HASRES) v += res[off];
                if (RELU)   v = fmaxf(v, 0.f);
                if (OUTBF)  ((u16*)Cp)[off] = f2bf(v);
                else        ((float*)Cp)[off] = v;
            }
        }
    }
}

extern "C" void kernel_launch(void* const* d_in, const int* in_sizes, int n_in,
                              void* d_out, int out_size, void* d_ws, size_t ws_size,
                              hipStream_t stream)
{
    const float* x    = (const float*)d_in[0];
    const float* ln1g = (const float*)d_in[1];
    const float* ln1b = (const float*)d_in[2];
    const float* Wk   = (const float*)d_in[3];
    const float* bk   = (const float*)d_in[4];
    const float* Wq   = (const float*)d_in[5];
    const float* bq   = (const float*)d_in[6];
    const float* Wv   = (const float*)d_in[7];
    const float* bv   = (const float*)d_in[8];
    const float* Wp   = (const float*)d_in[9];
    const float* bp   = (const float*)d_in[10];
    const float* ln2g = (const float*)d_in[11];
    const float* ln2b = (const float*)d_in[12];
    const float* W1   = (const float*)d_in[13];
    const float* b1   = (const float*)d_in[14];
    const float* W2   = (const float*)d_in[15];
    const float* b2   = (const float*)d_in[16];

    // ---- workspace carve-up ----
    char* ws = (char*)d_ws;
    size_t off = 0;
    auto alloc = [&](size_t bytes) -> char* {
        char* p = ws + off; off += (bytes + 255) & ~(size_t)255; return p;
    };
    u16*   wqkvT = (u16*)alloc((size_t)1152 * 384 * 2);
    u16*   wpT   = (u16*)alloc((size_t)384 * 384 * 2);
    u16*   w1T   = (u16*)alloc((size_t)1536 * 384 * 2);
    u16*   w2T   = (u16*)alloc((size_t)384 * 1536 * 2);
    float* bqkv  = (float*)alloc((size_t)1152 * 4);
    u16*   h     = (u16*)alloc((size_t)ROWS * CC * 2);             // LN1 out; reused: attnout, h2
    u16*   qkv   = (u16*)alloc((size_t)ROWS * 1152 * 2);           // Q|K|V; reused: x1 (fp32)
    u16* attnout = h;
    u16* h2      = h;
    float* x1    = (float*)qkv;        // 50.3 MB inside dead 75.5 MB qkv region
    // tail region: vt (25.2 MB) during attention, then ff (FFN activation)
    u16*   vt    = (u16*)(ws + off);
    u16*   ff    = vt;                 // ff aliases dead vt
    // Dynamic FFN chunking: one pass if ff (100.7 MB) fits, else 2 chunks
    // (ws_size is constant across calls -> same graph every capture).
    const size_t need_full = off + (size_t)ROWS * FFF * 2;
    const int nfc = (ws_size >= need_full) ? 1 : 2;
    const int fch = ROWS / nfc;

    // 1) LN1 + weight convert (fused, independent work)
    ln1_cvt_kernel<<<ROWS / 4 + 6918, 256, 0, stream>>>(
        x, ln1g, ln1b, h, Wq, Wk, Wv, bq, bk, bv, Wp, W1, W2,
        wqkvT, wpT, w1T, w2T, bqkv);
    // 2) QKV
    gemm_bt<128, 128, true, false, false><<<dim3(ROWS / 128, 1152 / 128, 1), 256, 0, stream>>>(
        h, wqkvT, qkv, bqkv, nullptr, 384, 384, 384, 1152,
        0, 0, 0, 0, 0, 0, 1, 1.f);
    // 3) V transpose
    vtrans_kernel<<<dim3(BB * HH, 4), 256, 0, stream>>>(qkv, vt);
    // 4) fused flash attention (quarter-granularity causal)
    flash_kernel<<<BB * HH * 4, 256, 0, stream>>>(qkv, vt, attnout);
    // 5) x1 = x + attnout @ Wp + bp   (x1 aliases dead qkv)
    gemm_bt<128, 128, false, false, true><<<dim3(ROWS / 128, CC / 128, 1), 256, 0, stream>>>(
        attnout, wpT, x1, bp, x, CC, CC, CC, CC,
        0, 0, 0, 0, 0, 0, 1, 1.f);
    // 6) LN2
    ln_kernel<<<ROWS / 4, 256, 0, stream>>>(x1, ln2g, ln2b, h2);
    // 7-8) FFN (1 or 2 chunks depending on ws_size; ff aliases dead vt)
    for (int fc = 0; fc < nfc; ++fc) {
        const long long ro = (long long)fc * fch;
        gemm_bt<128, 128, true, true, false><<<dim3(fch / 128, FFF / 128, 1), 256, 0, stream>>>(
            h2 + ro * CC, w1T, ff, b1, nullptr, CC, CC, CC, FFF,
            0, 0, 0, 0, 0, 0, 1, 1.f);
        gemm_bt<128, 128, false, false, true><<<dim3(fch / 128, CC / 128, 1), 256, 0, stream>>>(
            ff, w2T, (float*)d_out + ro * CC, b2, x1 + ro * CC, FFF, FFF, FFF, CC,
            0, 0, 0, 0, 0, 0, 1, 1.f);
    }
}

// Round 8
// 436.838 us; speedup vs baseline: 1.0888x; 1.0888x over previous
//
#include <hip/hip_runtime.h>
#include <stdint.h>

#define BB 128
#define TT 256
#define CC 384
#define HH 6
#define DD 64
#define FFF 1536
#define ROWS (BB*TT)   // 32768

typedef unsigned short u16;
typedef __bf16 bf8v __attribute__((ext_vector_type(8)));
typedef float f4v __attribute__((ext_vector_type(4)));

__device__ __forceinline__ float bf2f(u16 u) {
    unsigned int v = ((unsigned int)u) << 16;
    float f;
    __builtin_memcpy(&f, &v, 4);
    return f;
}
__device__ __forceinline__ u16 f2bf(float f) {
    unsigned int u;
    __builtin_memcpy(&u, &f, 4);
    u += 0x7fffu + ((u >> 16) & 1u);   // RNE; inputs finite
    return (u16)(u >> 16);
}

// async global->LDS 16B per lane; LDS dest must be wave-uniform base + lane*16
__device__ __forceinline__ void gload_lds16(const void* g, void* l) {
    __builtin_amdgcn_global_load_lds(
        (__attribute__((address_space(1))) void*)(g),
        (__attribute__((address_space(3))) void*)(l), 16, 0, 0);
}

// ---------------- LayerNorm: fp32 in -> bf16 out (1 wave per row of 384) ------
__device__ __forceinline__ void ln_body(
    int row, const float* __restrict__ x, const float* __restrict__ g,
    const float* __restrict__ b, u16* __restrict__ out, int lane)
{
    const float* xr = x + (long long)row * CC;
    float v[6]; float s = 0.f;
#pragma unroll
    for (int i = 0; i < 6; ++i) { v[i] = xr[lane + i * 64]; s += v[i]; }
#pragma unroll
    for (int o = 32; o > 0; o >>= 1) s += __shfl_xor(s, o);
    const float mu = s * (1.f / CC);
    float q = 0.f;
#pragma unroll
    for (int i = 0; i < 6; ++i) { float d = v[i] - mu; q += d * d; }
#pragma unroll
    for (int o = 32; o > 0; o >>= 1) q += __shfl_xor(q, o);
    const float inv = rsqrtf(q * (1.f / CC) + 1e-5f);
    u16* orow = out + (long long)row * CC;
#pragma unroll
    for (int i = 0; i < 6; ++i) {
        int c = lane + i * 64;
        orow[c] = f2bf((v[i] - mu) * inv * g[c] + b[c]);
    }
}

__global__ __launch_bounds__(256) void ln_kernel(
    const float* __restrict__ x, const float* __restrict__ g,
    const float* __restrict__ b, u16* __restrict__ out)
{
    ln_body(blockIdx.x * 4 + (threadIdx.x >> 6), x, g, b, out, threadIdx.x & 63);
}

// ---------------- fused LN1 + weight convert (independent work, one dispatch) -
__global__ __launch_bounds__(256) void ln1_cvt_kernel(
    const float* __restrict__ x, const float* __restrict__ ln1g, const float* __restrict__ ln1b,
    u16* __restrict__ h,
    const float* __restrict__ Wq, const float* __restrict__ Wk, const float* __restrict__ Wv,
    const float* __restrict__ bq, const float* __restrict__ bk, const float* __restrict__ bv,
    const float* __restrict__ Wp, const float* __restrict__ W1, const float* __restrict__ W2,
    u16* __restrict__ wqkvT, u16* __restrict__ wpT, u16* __restrict__ w1T,
    u16* __restrict__ w2T, float* __restrict__ bqkv)
{
    if (blockIdx.x < ROWS / 4) {
        ln_body(blockIdx.x * 4 + (threadIdx.x >> 6), x, ln1g, ln1b, h, threadIdx.x & 63);
        return;
    }
    const int S0 = 1152 * 384, S1 = 384 * 384, S2 = 1536 * 384, S3 = 384 * 1536;
    int i = (blockIdx.x - ROWS / 4) * 256 + threadIdx.x;
    if (i < S0) {
        int n = i / 384, k = i % 384;
        const float* W = (n < 384) ? Wq : (n < 768) ? Wk : Wv;
        int nn = (n >= 768) ? n - 768 : (n >= 384) ? n - 384 : n;
        int hh = nn >> 6, d = nn & 63;
        wqkvT[i] = f2bf(W[hh * (384 * 64) + k * 64 + d]);
        return;
    }
    i -= S0;
    if (i < S1) { int n = i / 384, k = i % 384; wpT[i] = f2bf(Wp[k * 384 + n]); return; }
    i -= S1;
    if (i < S2) { int n = i / 384, k = i % 384; w1T[i] = f2bf(W1[k * 1536 + n]); return; }
    i -= S2;
    if (i < S3) { int n = i / 1536, k = i % 1536; w2T[i] = f2bf(W2[k * 384 + n]); return; }
    i -= S3;
    if (i < 1152) bqkv[i] = (i < 384) ? bq[i] : (i < 768) ? bk[i - 384] : bv[i - 768];
}

// ---------------- V transpose: qkv (b,t,h,d) V-cols -> vt (b,h,d,t) ----------
__global__ __launch_bounds__(256) void vtrans_kernel(
    const u16* __restrict__ qkv, u16* __restrict__ vt)
{
    __shared__ u16 tile[64][65];
    const int z = blockIdx.x;          // b*H + h
    const int tb = blockIdx.y;         // t-block of 64
    const int zb = z / HH, zh = z % HH;
    const u16* src = qkv + ((long long)(zb * TT + tb * 64)) * 1152 + 768 + zh * 64;
    const int tid = threadIdx.x;
#pragma unroll
    for (int it = 0; it < 16; ++it) {
        int idx = it * 256 + tid; int tl = idx >> 6, d = idx & 63;
        tile[tl][d] = src[(long long)tl * 1152 + d];
    }
    __syncthreads();
    u16* dst = vt + (long long)z * 64 * 256 + tb * 64;
#pragma unroll
    for (int it = 0; it < 16; ++it) {
        int idx = it * 256 + tid; int d = idx >> 6, tl = idx & 63;
        dst[(long long)d * 256 + tl] = tile[tl][d];
    }
}

// ---------------- Fused flash-style causal attention --------------------------
// R8: back to R4's proven shape (128-row half-blocks, 4 waves x 32-row strips;
// R7's 16-row strips halved ILP and regressed). NEW: Q and V tiles staged in
// LDS once per block via global_load_lds (R3/R6-proven mechanism) — kills the
// 4x-redundant per-wave global fragment gathers that made R4/R7 latency-bound.
// XOR granule swizzle p = g ^ (row&7) spreads b128 fragment reads across all
// 8 bank groups (R6 measured 0 conflicts with the same trick). ntiles is
// wave-uniform per block so the 2 barriers/tile are safe.
__global__ __launch_bounds__(256) void flash_kernel(
    const u16* __restrict__ qkv, const u16* __restrict__ vt, u16* __restrict__ attnout)
{
    __shared__ __align__(16) u16 Qs[64 * 64];    // 8 KB, swizzled granules
    __shared__ __align__(16) u16 Vs[64 * 64];    // 8 KB, swizzled granules
    __shared__ __align__(16) u16 Pl[128 * 72];   // 18.4 KB, wave-private rows

    const int blk = blockIdx.x;
    const int bh = blk >> 1, half = blk & 1;     // interleave long/short blocks
    const int b = bh / HH, hh = bh % HH;
    const int tid = threadIdx.x;
    const int wave = tid >> 6, lane = tid & 63;
    const int quad = lane >> 4, lq = lane & 15;
    const int t0 = half * 128;

    const long long qrow = (long long)b * TT * 1152;
    const u16* Kb  = qkv + qrow + 384 + hh * 64;   // K segment cols
    const u16* Qb  = qkv + qrow + hh * 64;         // Q segment cols
    const u16* Vtb = vt + (long long)bh * (DD * TT);

    // K fragments for this wave's 32-row strip (A operand), loaded once
    bf8v af[2][2];
#pragma unroll
    for (int i = 0; i < 2; ++i)
#pragma unroll
        for (int ks = 0; ks < 2; ++ks)
            af[i][ks] = *(const bf8v*)(Kb + (long long)(t0 + wave * 32 + i * 16 + lq) * 1152
                                          + ks * 32 + quad * 8);

    float m_run[2][4], l_run[2][4];
    f4v oacc[2][4];
#pragma unroll
    for (int i = 0; i < 2; ++i) {
#pragma unroll
        for (int r = 0; r < 4; ++r) { m_run[i][r] = -1e30f; l_run[i][r] = 0.f; }
#pragma unroll
        for (int j = 0; j < 4; ++j) oacc[i][j] = (f4v){0.f, 0.f, 0.f, 0.f};
    }

    const float scs = 0.05103103630798287f;  // 384^-0.5 (faithful quirk)
    const int ntiles = 2 * (half + 1);       // causal: half0 -> 2 tiles, half1 -> 4
    for (int st = 0; st < ntiles; ++st) {
        const int s0 = st * 64;
        __syncthreads();   // previous tile's Qs/Vs reads complete
        // stage Q tile (rows = keys s0..s0+63, 64 cols) and V tile (rows = d,
        // cols = s0..s0+63), 128 B/row coalesced, swizzled granules
#pragma unroll
        for (int it = 0; it < 2; ++it) {
            int idx = it * 256 + tid; int r = idx >> 3, pg = idx & 7;
            int lg = pg ^ (r & 7);
            gload_lds16(Qb + (long long)(s0 + r) * 1152 + lg * 8, Qs + idx * 8);
        }
#pragma unroll
        for (int it = 0; it < 2; ++it) {
            int idx = it * 256 + tid; int r = idx >> 3, pg = idx & 7;
            int lg = pg ^ (r & 7);
            gload_lds16(Vtb + (long long)r * 256 + s0 + lg * 8, Vs + idx * 8);
        }
        __syncthreads();   // DMA drain

        // ---- S-tile: 64 rows x 64 s, K=64 (Q from LDS) ----
        f4v sacc[2][4];
#pragma unroll
        for (int i = 0; i < 2; ++i)
#pragma unroll
            for (int j = 0; j < 4; ++j) sacc[i][j] = (f4v){0.f, 0.f, 0.f, 0.f};
#pragma unroll
        for (int ks = 0; ks < 2; ++ks) {
            bf8v bq[4];
#pragma unroll
            for (int j = 0; j < 4; ++j) {
                int row = j * 16 + lq;
                int p = (ks * 4 + quad) ^ (row & 7);
                bq[j] = *(const bf8v*)(Qs + row * 64 + p * 8);
            }
#pragma unroll
            for (int i = 0; i < 2; ++i)
#pragma unroll
                for (int j = 0; j < 4; ++j)
                    sacc[i][j] = __builtin_amdgcn_mfma_f32_16x16x32_bf16(af[i][ks], bq[j], sacc[i][j], 0, 0, 0);
        }
        // ---- scale + causal mask (C layout: row=quad*4+r, col=lq) ----
#pragma unroll
        for (int i = 0; i < 2; ++i)
#pragma unroll
            for (int j = 0; j < 4; ++j)
#pragma unroll
                for (int r = 0; r < 4; ++r) {
                    int t_g = t0 + wave * 32 + i * 16 + quad * 4 + r;
                    int s_g = s0 + j * 16 + lq;
                    float v = sacc[i][j][r] * scs;
                    sacc[i][j][r] = (s_g <= t_g) ? v : -1e30f;
                }
        // ---- online softmax (per row (i,r); row spans j x lq) ----
#pragma unroll
        for (int i = 0; i < 2; ++i)
#pragma unroll
            for (int r = 0; r < 4; ++r) {
                float mt = sacc[i][0][r];
#pragma unroll
                for (int j = 1; j < 4; ++j) mt = fmaxf(mt, sacc[i][j][r]);
#pragma unroll
                for (int o = 8; o > 0; o >>= 1) mt = fmaxf(mt, __shfl_xor(mt, o));
                const float mn = fmaxf(m_run[i][r], mt);
                const float alpha = __expf(m_run[i][r] - mn);
                float rs = 0.f;
#pragma unroll
                for (int j = 0; j < 4; ++j) {
                    float e = __expf(sacc[i][j][r] - mn);
                    sacc[i][j][r] = e; rs += e;
                }
#pragma unroll
                for (int o = 8; o > 0; o >>= 1) rs += __shfl_xor(rs, o);
                m_run[i][r] = mn;
                l_run[i][r] = l_run[i][r] * alpha + rs;
#pragma unroll
                for (int j = 0; j < 4; ++j) oacc[i][j][r] *= alpha;
            }
        // ---- P: C layout -> A layout via wave-private LDS rows (no barrier) ----
#pragma unroll
        for (int i = 0; i < 2; ++i)
#pragma unroll
            for (int j = 0; j < 4; ++j)
#pragma unroll
                for (int r = 0; r < 4; ++r)
                    Pl[(wave * 32 + i * 16 + quad * 4 + r) * 72 + j * 16 + lq] = f2bf(sacc[i][j][r]);
        // ---- PV partial: out += P(32x64) @ V(64x64), V from LDS ----
#pragma unroll
        for (int ks2 = 0; ks2 < 2; ++ks2) {
            bf8v ap[2], bv_[4];
#pragma unroll
            for (int i = 0; i < 2; ++i)
                ap[i] = *(const bf8v*)(Pl + (wave * 32 + i * 16 + lq) * 72 + ks2 * 32 + quad * 8);
#pragma unroll
            for (int j = 0; j < 4; ++j) {
                int row = j * 16 + lq;
                int p = (ks2 * 4 + quad) ^ (row & 7);
                bv_[j] = *(const bf8v*)(Vs + row * 64 + p * 8);
            }
#pragma unroll
            for (int i = 0; i < 2; ++i)
#pragma unroll
                for (int j = 0; j < 4; ++j)
                    oacc[i][j] = __builtin_amdgcn_mfma_f32_16x16x32_bf16(ap[i], bv_[j], oacc[i][j], 0, 0, 0);
        }
    }
    // ---- epilogue: normalize by l, scatter into (b,t,h*64+d) ----
#pragma unroll
    for (int i = 0; i < 2; ++i)
#pragma unroll
        for (int r = 0; r < 4; ++r) {
            const float inv = 1.f / l_run[i][r];
            u16* orow = attnout + ((long long)(b * TT + t0 + wave * 32 + i * 16 + quad * 4 + r)) * CC + hh * 64;
#pragma unroll
            for (int j = 0; j < 4; ++j)
                orow[j * 16 + lq] = f2bf(oacc[i][j][r] * inv);
        }
}

// ---------------- Generic bf16 MFMA GEMM: C = scale*(A @ B^T) [+bias][+res][relu]
// R6-proven: BK=32, global_load_lds width-16, XOR granule swizzle (0 bank
// conflicts). Drain-limited at thin K (m97 plateau) — inner loop frozen.
template<int BM, int BN, bool OUTBF, bool RELU, bool HASRES>
__global__ __launch_bounds__(256) void gemm_bt(
    const u16* __restrict__ A, const u16* __restrict__ Bw, void* __restrict__ Cp,
    const float* __restrict__ bias, const float* __restrict__ res,
    int K, int lda, int ldb, int ldc,
    long long sAb, long long sAh, long long sBb, long long sBh,
    long long sCb, long long sCh, int Hb, float scale)
{
    __shared__ __align__(16) u16 As[BM * 32];
    __shared__ __align__(16) u16 Bs[BN * 32];

    const int tid = threadIdx.x;
    const int wave = tid >> 6, lane = tid & 63;
    const int quad = lane >> 4, lq = lane & 15;

    const int z = blockIdx.z;
    const int zb = z / Hb, zh = z % Hb;
    const int m0 = blockIdx.x * BM;
    const int n0 = blockIdx.y * BN;

    A  += (long long)zb * sAb + (long long)zh * sAh + (long long)m0 * lda;
    Bw += (long long)zb * sBb + (long long)zh * sBh + (long long)n0 * ldb;
    const long long coff = (long long)zb * sCb + (long long)zh * sCh;

    constexpr int WM = BM / 2, WN = BN / 2;
    constexpr int MT = WM / 16, NT = WN / 16;
    const int wm0 = (wave >> 1) * WM;
    const int wn0 = (wave & 1) * WN;

    f4v acc[MT][NT];
#pragma unroll
    for (int i = 0; i < MT; ++i)
#pragma unroll
        for (int j = 0; j < NT; ++j) acc[i][j] = (f4v){0.f, 0.f, 0.f, 0.f};

    constexpr int AIT = BM / 64;
    constexpr int BIT = BN / 64;

    for (int k0 = 0; k0 < K; k0 += 32) {
        __syncthreads();   // previous iteration's LDS reads complete before overwrite
#pragma unroll
        for (int j = 0; j < AIT; ++j) {
            int idx = j * 256 + tid; int r = idx >> 2, pg = idx & 3;
            int lg = pg ^ ((r >> 1) & 3);        // fetch swizzled granule
            gload_lds16(A + (long long)r * lda + k0 + lg * 8, As + idx * 8);
        }
#pragma unroll
        for (int j = 0; j < BIT; ++j) {
            int idx = j * 256 + tid; int r = idx >> 2, pg = idx & 3;
            int lg = pg ^ ((r >> 1) & 3);
            gload_lds16(Bw + (long long)r * ldb + k0 + lg * 8, Bs + idx * 8);
        }
        __syncthreads();

        bf8v af[MT], bfr[NT];
#pragma unroll
        for (int i = 0; i < MT; ++i) {
            int row = wm0 + i * 16 + lq;
            int pg = quad ^ ((row >> 1) & 3);
            af[i] = *(const bf8v*)(As + row * 32 + pg * 8);
        }
#pragma unroll
        for (int j = 0; j < NT; ++j) {
            int row = wn0 + j * 16 + lq;
            int pg = quad ^ ((row >> 1) & 3);
            bfr[j] = *(const bf8v*)(Bs + row * 32 + pg * 8);
        }
#pragma unroll
        for (int i = 0; i < MT; ++i)
#pragma unroll
            for (int j = 0; j < NT; ++j)
                acc[i][j] = __builtin_amdgcn_mfma_f32_16x16x32_bf16(af[i], bfr[j], acc[i][j], 0, 0, 0);
    }

#pragma unroll
    for (int i = 0; i < MT; ++i) {
#pragma unroll
        for (int j = 0; j < NT; ++j) {
            const int gcol = n0 + wn0 + j * 16 + lq;
            const float bcol = bias ? bias[gcol] : 0.f;
#pragma unroll
            for (int r = 0; r < 4; ++r) {
                const int grow = m0 + wm0 + i * 16 + quad * 4 + r;
                const long long off = coff + (long long)grow * ldc + gcol;
                float v = acc[i][j][r] * scale + bcol;
                if (HASRES) v += res[off];
                if (RELU)   v = fmaxf(v, 0.f);
                if (OUTBF)  ((u16*)Cp)[off] = f2bf(v);
                else        ((float*)Cp)[off] = v;
            }
        }
    }
}

extern "C" void kernel_launch(void* const* d_in, const int* in_sizes, int n_in,
                              void* d_out, int out_size, void* d_ws, size_t ws_size,
                              hipStream_t stream)
{
    const float* x    = (const float*)d_in[0];
    const float* ln1g = (const float*)d_in[1];
    const float* ln1b = (const float*)d_in[2];
    const float* Wk   = (const float*)d_in[3];
    const float* bk   = (const float*)d_in[4];
    const float* Wq   = (const float*)d_in[5];
    const float* bq   = (const float*)d_in[6];
    const float* Wv   = (const float*)d_in[7];
    const float* bv   = (const float*)d_in[8];
    const float* Wp   = (const float*)d_in[9];
    const float* bp   = (const float*)d_in[10];
    const float* ln2g = (const float*)d_in[11];
    const float* ln2b = (const float*)d_in[12];
    const float* W1   = (const float*)d_in[13];
    const float* b1   = (const float*)d_in[14];
    const float* W2   = (const float*)d_in[15];
    const float* b2   = (const float*)d_in[16];

    // ---- workspace carve-up ----
    char* ws = (char*)d_ws;
    size_t off = 0;
    auto alloc = [&](size_t bytes) -> char* {
        char* p = ws + off; off += (bytes + 255) & ~(size_t)255; return p;
    };
    u16*   wqkvT = (u16*)alloc((size_t)1152 * 384 * 2);
    u16*   wpT   = (u16*)alloc((size_t)384 * 384 * 2);
    u16*   w1T   = (u16*)alloc((size_t)1536 * 384 * 2);
    u16*   w2T   = (u16*)alloc((size_t)384 * 1536 * 2);
    float* bqkv  = (float*)alloc((size_t)1152 * 4);
    u16*   h     = (u16*)alloc((size_t)ROWS * CC * 2);             // LN1 out; reused: attnout, h2
    u16*   qkv   = (u16*)alloc((size_t)ROWS * 1152 * 2);           // Q|K|V; reused: x1 (fp32)
    u16* attnout = h;
    u16* h2      = h;
    float* x1    = (float*)qkv;        // 50.3 MB inside dead 75.5 MB qkv region
    // tail region: vt (25.2 MB) during attention, then ff (FFN activation)
    u16*   vt    = (u16*)(ws + off);
    u16*   ff    = vt;                 // ff aliases dead vt
    // Dynamic FFN chunking: one pass if ff (100.7 MB) fits, else 2 chunks
    const size_t need_full = off + (size_t)ROWS * FFF * 2;
    const int nfc = (ws_size >= need_full) ? 1 : 2;
    const int fch = ROWS / nfc;

    // 1) LN1 + weight convert (fused, independent work)
    ln1_cvt_kernel<<<ROWS / 4 + 6918, 256, 0, stream>>>(
        x, ln1g, ln1b, h, Wq, Wk, Wv, bq, bk, bv, Wp, W1, W2,
        wqkvT, wpT, w1T, w2T, bqkv);
    // 2) QKV
    gemm_bt<128, 128, true, false, false><<<dim3(ROWS / 128, 1152 / 128, 1), 256, 0, stream>>>(
        h, wqkvT, qkv, bqkv, nullptr, 384, 384, 384, 1152,
        0, 0, 0, 0, 0, 0, 1, 1.f);
    // 3) V transpose
    vtrans_kernel<<<dim3(BB * HH, 4), 256, 0, stream>>>(qkv, vt);
    // 4) fused flash attention (128-row halves, LDS-staged Q/V)
    flash_kernel<<<BB * HH * 2, 256, 0, stream>>>(qkv, vt, attnout);
    // 5) x1 = x + attnout @ Wp + bp   (x1 aliases dead qkv)
    gemm_bt<128, 128, false, false, true><<<dim3(ROWS / 128, CC / 128, 1), 256, 0, stream>>>(
        attnout, wpT, x1, bp, x, CC, CC, CC, CC,
        0, 0, 0, 0, 0, 0, 1, 1.f);
    // 6) LN2
    ln_kernel<<<ROWS / 4, 256, 0, stream>>>(x1, ln2g, ln2b, h2);
    // 7-8) FFN (1 or 2 chunks depending on ws_size; ff aliases dead vt)
    for (int fc = 0; fc < nfc; ++fc) {
        const long long ro = (long long)fc * fch;
        gemm_bt<128, 128, true, true, false><<<dim3(fch / 128, FFF / 128, 1), 256, 0, stream>>>(
            h2 + ro * CC, w1T, ff, b1, nullptr, CC, CC, CC, FFF,
            0, 0, 0, 0, 0, 0, 1, 1.f);
        gemm_bt<128, 128, false, false, true><<<dim3(fch / 128, CC / 128, 1), 256, 0, stream>>>(
            ff, w2T, (float*)d_out + ro * CC, b2, x1 + ro * CC, FFF, FFF, FFF, CC,
            0, 0, 0, 0, 0, 0, 1, 1.f);
    }
}